// Round 18
// baseline (155.804 us; speedup 1.0000x reference)
//
#include <hip/hip_runtime.h>
#include <math.h>

#define DIM 256
#define BATCH 16
#define NO 64
#define NI 512
#define NEG_SLOPE 0.01f
#define CSCALE 2.885390081777927f   // 2*log2(e): tanh(x) = 1 - 2/(exp2(CSCALE*x)+1)
#define OT 2                        // o's per attn thread

// ---------------------------------------------------------------------------
// Kernel 1: GEMM  out[r,h] = sum_d A[r,d] * W1[h, coff+d]
//   q-tiles (mt 0..15):  Eq[bo][h] = exp2(CSCALE*(acc + b1[h]))
//   k-tiles (mt 16..143): MASK-COMPACTED — tile covers compacted rows
//     [r0b, r0b+64) of batch b; inline ballot-prefix scan of mask[b].
//     Ek4[b][h/4][j][4] = exp2(CSCALE*acc) at compacted slot j.
// 64x64 tile, K-chunk 64, 4x4 microtile. Blocks 576..591: Wf -> WfT.
// ---------------------------------------------------------------------------
__global__ __launch_bounds__(256, 4) void proj_kernel(
    const float* __restrict__ q, const float* __restrict__ k,
    const float* __restrict__ W1, const float* __restrict__ b1,
    const float* __restrict__ Wf, const int* __restrict__ mask,
    float* __restrict__ Eq, float* __restrict__ Ek4, float* __restrict__ WfT)
{
  __shared__ float smem[8704];   // 34 KB: At[64][68] + Wt[64][68]
  __shared__ int   idxT[64];
  __shared__ int   wtot[8];

  const int t  = threadIdx.x;
  const int bx = blockIdx.x;

  if (bx >= 576) {
    const int tt = bx - 576;
    const int tr = tt >> 2, tc = tt & 3;
#pragma unroll
    for (int p = 0; p < 4; ++p) {
      int idx2 = p * 256 + t;
      int row = idx2 >> 4, j = idx2 & 15;
      float4 vv = *(const float4*)(Wf + (size_t)(tr * 64 + row) * 256 + tc * 64 + j * 4);
      *(float4*)&smem[row * 68 + j * 4] = vv;
    }
    __syncthreads();
#pragma unroll
    for (int p = 0; p < 4; ++p) {
      int idx2 = p * 256 + t;
      int row = idx2 >> 4, j = idx2 & 15;
      float4 ov;
      ov.x = smem[(j * 4 + 0) * 68 + row];
      ov.y = smem[(j * 4 + 1) * 68 + row];
      ov.z = smem[(j * 4 + 2) * 68 + row];
      ov.w = smem[(j * 4 + 3) * 68 + row];
      *(float4*)(WfT + (size_t)(tc * 64 + row) * 256 + tr * 64 + j * 4) = ov;
    }
    return;
  }

  const int mt = bx >> 2;          // 0..143
  const int nt = bx & 3;
  const int h0 = nt * 64;
  const bool isq = (mt < 16);
  const int lane = t & 63;
  const int wid4 = t >> 6;         // 0..3

  int b = 0, r0b = 0, cntb = 0;
  const float* src = nullptr;
  if (isq) {
    src = q + (size_t)(mt * 64) * DIM;
  } else {
    const int kt = mt - 16;        // 0..127
    b   = kt >> 3;
    r0b = (kt & 7) * 64;           // compacted row base in batch b
    // ---- inline mask scan: thread t covers cols t and t+256 ----
    const int* maskb = mask + b * NI;
    int m0 = (maskb[t] == 0) ? 1 : 0;
    int m1 = (maskb[t + 256] == 0) ? 1 : 0;
    unsigned long long bl0 = __ballot(m0);
    unsigned long long bl1 = __ballot(m1);
    if (lane == 0) { wtot[wid4] = __popcll(bl0); wtot[4 + wid4] = __popcll(bl1); }
    if (t < 64) idxT[t] = 0;       // safe default (clamped rows -> row 0)
    __syncthreads();
    int pre[9];
    pre[0] = 0;
#pragma unroll
    for (int w = 0; w < 8; ++w) pre[w + 1] = pre[w] + wtot[w];
    cntb = pre[8];
    if (r0b >= cntb) return;       // tile fully masked away (uniform exit)
    unsigned long long lt = (1ull << lane) - 1ull;
    int p0 = pre[wid4] + __popcll(bl0 & lt);
    int p1 = pre[4 + wid4] + __popcll(bl1 & lt);
    if (m0 && p0 >= r0b && p0 < r0b + 64) idxT[p0 - r0b] = t;
    if (m1 && p1 >= r0b && p1 < r0b + 64) idxT[p1 - r0b] = t + 256;
    // main loop's first __syncthreads covers idxT visibility
  }

  float* At = smem;            // At[dk][row], stride 68
  float* Wt = smem + 4352;     // Wt[dk][h],   stride 68

  const int tx = t & 15;
  const int ty = t >> 4;
  const int coff = isq ? 0 : DIM;

  float acc[4][4] = {};

  for (int c0 = 0; c0 < DIM; c0 += 64) {
    __syncthreads();
#pragma unroll
    for (int p = 0; p < 4; ++p) {
      int idx2 = p * 256 + t;
      int row = idx2 >> 4, j = idx2 & 15;
      float4 av;
      if (isq) av = *(const float4*)(src + (size_t)row * DIM + c0 + j * 4);
      else     av = *(const float4*)(k + (size_t)(b * NI + idxT[row]) * DIM + c0 + j * 4);
      At[(4 * j + 0) * 68 + row] = av.x;
      At[(4 * j + 1) * 68 + row] = av.y;
      At[(4 * j + 2) * 68 + row] = av.z;
      At[(4 * j + 3) * 68 + row] = av.w;
      float4 wv = *(const float4*)(W1 + (size_t)(h0 + row) * (2 * DIM) + coff + c0 + j * 4);
      Wt[(4 * j + 0) * 68 + row] = wv.x;
      Wt[(4 * j + 1) * 68 + row] = wv.y;
      Wt[(4 * j + 2) * 68 + row] = wv.z;
      Wt[(4 * j + 3) * 68 + row] = wv.w;
    }
    __syncthreads();
#pragma unroll
    for (int dk = 0; dk < 64; ++dk) {
      float4 a4 = *(const float4*)&At[dk * 68 + ty * 4];
      float4 w4 = *(const float4*)&Wt[dk * 68 + tx * 4];
      const float ar[4] = {a4.x, a4.y, a4.z, a4.w};
      const float wr[4] = {w4.x, w4.y, w4.z, w4.w};
#pragma unroll
      for (int rr = 0; rr < 4; ++rr)
#pragma unroll
        for (int cc = 0; cc < 4; ++cc)
          acc[rr][cc] = fmaf(ar[rr], wr[cc], acc[rr][cc]);
    }
  }

  if (isq) {
    float4 bv = *(const float4*)(b1 + h0 + tx * 4);
    const float br[4] = {bv.x, bv.y, bv.z, bv.w};
#pragma unroll
    for (int rr = 0; rr < 4; ++rr) {
      int r = mt * 64 + ty * 4 + rr;
      float4 ov;
      ov.x = __builtin_amdgcn_exp2f((acc[rr][0] + br[0]) * CSCALE);
      ov.y = __builtin_amdgcn_exp2f((acc[rr][1] + br[1]) * CSCALE);
      ov.z = __builtin_amdgcn_exp2f((acc[rr][2] + br[2]) * CSCALE);
      ov.w = __builtin_amdgcn_exp2f((acc[rr][3] + br[3]) * CSCALE);
      *(float4*)(Eq + (size_t)r * DIM + h0 + tx * 4) = ov;
    }
  } else {
    // Ek4 layout (compacted): Ek4[((b*64 + h/4)*NI + j)*4 + (h&3)]
    int j0  = r0b + ty * 4;
    int hq0 = (h0 >> 2) + tx;
#pragma unroll
    for (int rr = 0; rr < 4; ++rr) {
      int j = j0 + rr;
      if (j < cntb) {
        float4 ov;
        ov.x = __builtin_amdgcn_exp2f(acc[rr][0] * CSCALE);
        ov.y = __builtin_amdgcn_exp2f(acc[rr][1] * CSCALE);
        ov.z = __builtin_amdgcn_exp2f(acc[rr][2] * CSCALE);
        ov.w = __builtin_amdgcn_exp2f(acc[rr][3] * CSCALE);
        *(float4*)(Ek4 + ((size_t)(b * 64 + hq0) * NI + j) * 4) = ov;
      }
    }
  }
}

__device__ __forceinline__ void f4arr(float4 v, float* a) {
  a[0] = v.x; a[1] = v.y; a[2] = v.z; a[3] = v.w;
}

// ---------------------------------------------------------------------------
// Kernel 2: one block (512 threads) per (b, o-pair). Grid 512. XCD-swizzled.
// MASK-COMPACTED with INLINE scan. paired-rcp sigmoid; no-max softmax;
// PV over compacted rows with next-iter LDS hoist; phase 4 e-split across
// ALL 512 threads (no idle half) + LDS combine.
// ---------------------------------------------------------------------------
__global__ __launch_bounds__(512, 4) void attn_kernel(
    const float* __restrict__ Eq, const float* __restrict__ Ek4,
    const float* __restrict__ v, const int* __restrict__ mask,
    const float* __restrict__ W2, const float* __restrict__ b2,
    const float* __restrict__ WfT, const float* __restrict__ bf,
    float* __restrict__ out, float* __restrict__ attn_out)
{
  __shared__ float sc[OT][NI];        // 4 KB (compacted attn weights)
  __shared__ int   idxs[NI];          // 2 KB
  __shared__ float pvp[8][OT][DIM];   // 16 KB
  __shared__ float o0[OT][DIM];       // 2 KB
  __shared__ float fpart[2][OT][DIM]; // 4 KB
  __shared__ float red4[8][OT];
  __shared__ float redw[8];
  __shared__ int   wtot[8];

  const int t    = threadIdx.x;
  const int lane = t & 63;
  const int wid  = t >> 6;

  const int blk  = blockIdx.x;
  const int tile = (blk & 7) * 64 + (blk >> 3);   // XCD swizzle
  const int b    = tile >> 5;
  const int bo0  = b * 64 + (tile & 31) * OT;

  // ---- inline mask scan (thread t = original column t) ----
  const int unm = (mask[b * NI + t] == 0) ? 1 : 0;
  unsigned long long bal = __ballot(unm);
  int myIn = __popcll(bal & ((1ull << lane) - 1ull));
  if (lane == 0) wtot[wid] = __popcll(bal);
  __syncthreads();
  int pre = 0, cntb = 0;
#pragma unroll
  for (int w = 0; w < 8; ++w) {
    if (w < wid) pre += wtot[w];
    cntb += wtot[w];
  }
  const int myPos = unm ? (pre + myIn) : -1;
  if (unm) idxs[myPos] = t;
  // visibility of idxs: covered by the sumW2 barrier below

  // ---- sumW2 ----
  float partial = (t < DIM) ? W2[t] : 0.f;
#pragma unroll
  for (int off = 32; off >= 1; off >>= 1) partial += __shfl_xor(partial, off, 64);
  if (lane == 0) redw[wid] = partial;
  __syncthreads();
  float sumw2 = 0.f;
#pragma unroll
  for (int w = 0; w < 8; ++w) sumw2 += redw[w];
  const float base = sumw2 + b2[0];

  // ---- phase 1: scores for compacted column j = t (paired-rcp) ----
  const int j = t;
  const bool active = (j < cntb);
  const int jc = active ? j : (cntb > 0 ? cntb - 1 : 0);   // clamped safe index
  const float4* kb4 = (const float4*)Ek4 + (size_t)b * 64 * NI;  // [hq*NI + j]
  const float* qrow0 = Eq + (size_t)(bo0 + 0) * DIM;
  const float* qrow1 = Eq + (size_t)(bo0 + 1) * DIM;

  float acc0 = 0.f, acc1 = 0.f;
  if (wid * 64 < cntb) {                 // wave-uniform skip of dead waves
#pragma unroll 8
    for (int hq = 0; hq < 64; ++hq) {
      float4 kq = kb4[(size_t)hq * NI + jc];
      float wr[4], q0r[4], q1r[4], kv[4];
      f4arr(*(const float4*)(W2 + hq * 4), wr);      // wave-uniform -> s_load
      f4arr(*(const float4*)(qrow0 + hq * 4), q0r);
      f4arr(*(const float4*)(qrow1 + hq * 4), q1r);
      f4arr(kq, kv);
#pragma unroll
      for (int pr = 0; pr < 2; ++pr) {               // pairs (0,1), (2,3)
        const int ea = pr * 2, eb = pr * 2 + 1;
        float A0 = fmaf(q0r[ea], kv[ea], 1.f);
        float B0 = fmaf(q0r[eb], kv[eb], 1.f);
        float N0 = fmaf(wr[eb], A0, wr[ea] * B0);
        acc0 = fmaf(N0, __builtin_amdgcn_rcpf(A0 * B0), acc0);
        float A1 = fmaf(q1r[ea], kv[ea], 1.f);
        float B1 = fmaf(q1r[eb], kv[eb], 1.f);
        float N1 = fmaf(wr[eb], A1, wr[ea] * B1);
        acc1 = fmaf(N1, __builtin_amdgcn_rcpf(A1 * B1), acc1);
      }
    }
  }

  float s0 = active ? (base - 2.f * acc0) : -INFINITY;
  float s1 = active ? (base - 2.f * acc1) : -INFINITY;

  // ---- phase 2: softmax over compacted set, no max-subtraction ----
  // |s| <= sum|W2| + |b2| ~ 13 -> exp2 safe; exp2(-inf) = 0 for inactive.
  float p0 = __builtin_amdgcn_exp2f(s0 * 1.4426950408889634f);
  float p1 = __builtin_amdgcn_exp2f(s1 * 1.4426950408889634f);
  float ps0 = p0, ps1 = p1;
#pragma unroll
  for (int off = 32; off >= 1; off >>= 1) {
    ps0 += __shfl_xor(ps0, off, 64);
    ps1 += __shfl_xor(ps1, off, 64);
  }
  __syncthreads();               // redw reads done; red4 safe
  if (lane == 0) { red4[wid][0] = ps0; red4[wid][1] = ps1; }
  __syncthreads();
  float ss0 = 0.f, ss1 = 0.f;
#pragma unroll
  for (int w = 0; w < 8; ++w) { ss0 += red4[w][0]; ss1 += red4[w][1]; }
  const float a0 = p0 * __builtin_amdgcn_rcpf(ss0);
  const float a1 = p1 * __builtin_amdgcn_rcpf(ss1);
  sc[0][j] = a0;                 // compacted slot (0 for inactive j)
  sc[1][j] = a1;
  __syncthreads();

  // attn_out scatter-back: original column i = t; masked -> exact 0
  {
    float w0 = (myPos >= 0) ? sc[0][myPos] : 0.f;
    float w1 = (myPos >= 0) ? sc[1][myPos] : 0.f;
    attn_out[(size_t)(bo0 + 0) * NI + t] = w0;
    attn_out[(size_t)(bo0 + 1) * NI + t] = w1;
  }

  // ---- phase 3: PV over compacted rows. wave wid: j in [wid*64, +64)∩cnt.
  //      sc/idxs for the next row hoisted ahead of the fma chain. ----
  {
    const int d4 = lane;
    float4 av0 = {0.f, 0.f, 0.f, 0.f};
    float4 av1 = {0.f, 0.f, 0.f, 0.f};
    const float4* vb4 = (const float4*)(v + (size_t)b * NI * DIM);
    const int jbeg = wid * 64;
    const int jend = min(jbeg + 64, cntb);
    if (jbeg < jend) {
      int   rowN = idxs[jbeg];
      float sa0N = sc[0][jbeg], sa1N = sc[1][jbeg];
      for (int jb = jbeg; jb < jend; ++jb) {
        int   row = rowN;
        float sa0 = sa0N, sa1 = sa1N;
        if (jb + 1 < jend) {               // hoist next iter's LDS reads
          rowN = idxs[jb + 1];
          sa0N = sc[0][jb + 1];
          sa1N = sc[1][jb + 1];
        }
        float4 vv = vb4[(size_t)row * 64 + d4];
        av0.x = fmaf(sa0, vv.x, av0.x);
        av0.y = fmaf(sa0, vv.y, av0.y);
        av0.z = fmaf(sa0, vv.z, av0.z);
        av0.w = fmaf(sa0, vv.w, av0.w);
        av1.x = fmaf(sa1, vv.x, av1.x);
        av1.y = fmaf(sa1, vv.y, av1.y);
        av1.z = fmaf(sa1, vv.z, av1.z);
        av1.w = fmaf(sa1, vv.w, av1.w);
      }
    }
    *(float4*)&pvp[wid][0][d4 * 4] = av0;      // dead waves store zeros
    *(float4*)&pvp[wid][1][d4 * 4] = av1;
  }
  __syncthreads();
  {
    int oo = t >> 8, d = t & 255;
    float sacc = 0.f;
#pragma unroll
    for (int w = 0; w < 8; ++w) sacc += pvp[w][oo][d];
    o0[oo][d] = sacc;
  }
  __syncthreads();

  // ---- phase 4: e-split over ALL 512 threads: (half = t>>8, d = t&255),
  //      each does e in [half*128, half*128+128) for both o's ----
  {
    const int half = t >> 8;
    const int d    = t & 255;
    const int e0   = half * 128;
    float f0 = 0.f, f1 = 0.f;
#pragma unroll 8
    for (int e4 = 0; e4 < 32; ++e4) {
      float oa[4], ob[4];
      f4arr(*(const float4*)&o0[0][e0 + e4 * 4], oa);
      f4arr(*(const float4*)&o0[1][e0 + e4 * 4], ob);
#pragma unroll
      for (int c = 0; c < 4; ++c) {
        float wv = WfT[(size_t)(e0 + e4 * 4 + c) * DIM + d];
        f0 = fmaf(oa[c], wv, f0);
        f1 = fmaf(ob[c], wv, f1);
      }
    }
    fpart[half][0][d] = f0;
    fpart[half][1][d] = f1;
  }
  __syncthreads();
  {
    const int oo = t >> 8;           // 0..1, d = t&255: 512 threads = 2x256
    const int d  = t & 255;
    float f = fpart[0][oo][d] + fpart[1][oo][d] + bf[d];
    f = (f >= 0.f) ? f : NEG_SLOPE * f;
    out[(size_t)(bo0 + oo) * DIM + d] = f;
  }
}

// ---------------------------------------------------------------------------
extern "C" void kernel_launch(void* const* d_in, const int* in_sizes, int n_in,
                              void* d_out, int out_size, void* d_ws, size_t ws_size,
                              hipStream_t stream) {
  const float* q    = (const float*)d_in[0];
  const float* k    = (const float*)d_in[1];
  const float* v    = (const float*)d_in[2];
  const int*   mask = (const int*)d_in[3];
  const float* W1   = (const float*)d_in[4];
  const float* b1   = (const float*)d_in[5];
  const float* W2   = (const float*)d_in[6];
  const float* b2   = (const float*)d_in[7];
  const float* Wf   = (const float*)d_in[8];
  const float* bf   = (const float*)d_in[9];

  float* out      = (float*)d_out;                    // (16,64,256)
  float* attn_out = out + (size_t)BATCH * NO * DIM;   // (16,64,512)

  float* Eq   = (float*)d_ws;                         // 1024 x 256
  float* Ek4  = Eq + (size_t)BATCH * NO * DIM;        // 16 x 64 x 512 x 4
  float* WfT  = Ek4 + (size_t)BATCH * DIM * NI;       // 256 x 256

  proj_kernel<<<592, 256, 0, stream>>>(q, k, W1, b1, Wf, mask, Eq, Ek4, WfT);
  attn_kernel<<<(BATCH * NO) / OT, 512, 0, stream>>>(Eq, Ek4, v, mask,
                                                     W2, b2, WfT, bf, out, attn_out);
}

// Round 19
// 139.330 us; speedup vs baseline: 1.1182x; 1.1182x over previous
//
#include <hip/hip_runtime.h>
#include <math.h>

#define DIM 256
#define BATCH 16
#define NO 64
#define NI 512
#define NEG_SLOPE 0.01f
#define CSCALE 2.885390081777927f   // 2*log2(e): tanh(x) = 1 - 2/(exp2(CSCALE*x)+1)
#define OT 2                        // o's per attn thread

// ---------------------------------------------------------------------------
// Kernel 0: per-batch mask compaction. cnt[b] = #unmasked, idx[b][j] = i of
// j-th unmasked column, pos[b][i] = compacted slot (or -1 if masked).
// ---------------------------------------------------------------------------
__global__ __launch_bounds__(512) void mask_scan_kernel(
    const int* __restrict__ mask, int* __restrict__ idx,
    int* __restrict__ posArr, int* __restrict__ cnt)
{
  __shared__ int wtot[8];
  __shared__ int woff[8];
  const int b = blockIdx.x, t = threadIdx.x;
  const int lane = t & 63, wid = t >> 6;
  const int unm = (mask[b * NI + t] == 0) ? 1 : 0;
  unsigned long long bal = __ballot(unm);
  int my  = __popcll(bal & ((1ull << lane) - 1ull));
  if (lane == 0) wtot[wid] = __popcll(bal);
  __syncthreads();
  if (t == 0) {
    int acc = 0;
    for (int w = 0; w < 8; ++w) { woff[w] = acc; acc += wtot[w]; }
    cnt[b] = acc;
  }
  __syncthreads();
  int pos = woff[wid] + my;
  if (unm) idx[b * NI + pos] = t;
  posArr[b * NI + t] = unm ? pos : -1;
}

// ---------------------------------------------------------------------------
// Kernel 1: GEMM  out[r,h] = sum_d A[r,d] * W1[h, coff+d]
//   q-tiles:  Eq[bo][h] = exp2(CSCALE*(acc + b1[h]))
//   k-tiles:  Ek4[b][h/4][pos[i]][4] = exp2(CSCALE*acc)  (compacted store)
// 64x64 tile, K-chunk 64, 4x4 microtile. Blocks 576..591: Wf -> WfT.
// ---------------------------------------------------------------------------
__global__ __launch_bounds__(256, 4) void proj_kernel(
    const float* __restrict__ q, const float* __restrict__ k,
    const float* __restrict__ W1, const float* __restrict__ b1,
    const float* __restrict__ Wf, const int* __restrict__ posArr,
    float* __restrict__ Eq, float* __restrict__ Ek4, float* __restrict__ WfT)
{
  __shared__ float smem[8704];   // 34 KB: At[64][68] + Wt[64][68]

  const int t  = threadIdx.x;
  const int bx = blockIdx.x;

  if (bx >= 576) {
    const int tt = bx - 576;
    const int tr = tt >> 2, tc = tt & 3;
#pragma unroll
    for (int p = 0; p < 4; ++p) {
      int idx2 = p * 256 + t;
      int row = idx2 >> 4, j = idx2 & 15;
      float4 vv = *(const float4*)(Wf + (size_t)(tr * 64 + row) * 256 + tc * 64 + j * 4);
      *(float4*)&smem[row * 68 + j * 4] = vv;
    }
    __syncthreads();
#pragma unroll
    for (int p = 0; p < 4; ++p) {
      int idx2 = p * 256 + t;
      int row = idx2 >> 4, j = idx2 & 15;
      float4 ov;
      ov.x = smem[(j * 4 + 0) * 68 + row];
      ov.y = smem[(j * 4 + 1) * 68 + row];
      ov.z = smem[(j * 4 + 2) * 68 + row];
      ov.w = smem[(j * 4 + 3) * 68 + row];
      *(float4*)(WfT + (size_t)(tc * 64 + row) * 256 + tr * 64 + j * 4) = ov;
    }
    return;
  }

  float* At = smem;            // At[dk][row], stride 68
  float* Wt = smem + 4352;     // Wt[dk][h],   stride 68

  const int tx = t & 15;
  const int ty = t >> 4;
  const int mt = bx >> 2;
  const int nt = bx & 3;
  const int r0 = mt * 64;
  const int h0 = nt * 64;
  const bool isq = (r0 < BATCH * NO);
  const float* src = isq ? (q + (size_t)r0 * DIM)
                         : (k + (size_t)(r0 - BATCH * NO) * DIM);
  const int coff = isq ? 0 : DIM;

  float acc[4][4] = {};

  for (int c0 = 0; c0 < DIM; c0 += 64) {
    __syncthreads();
#pragma unroll
    for (int p = 0; p < 4; ++p) {
      int idx2 = p * 256 + t;
      int row = idx2 >> 4, j = idx2 & 15;
      float4 av = *(const float4*)(src + (size_t)row * DIM + c0 + j * 4);
      At[(4 * j + 0) * 68 + row] = av.x;
      At[(4 * j + 1) * 68 + row] = av.y;
      At[(4 * j + 2) * 68 + row] = av.z;
      At[(4 * j + 3) * 68 + row] = av.w;
      float4 wv = *(const float4*)(W1 + (size_t)(h0 + row) * (2 * DIM) + coff + c0 + j * 4);
      Wt[(4 * j + 0) * 68 + row] = wv.x;
      Wt[(4 * j + 1) * 68 + row] = wv.y;
      Wt[(4 * j + 2) * 68 + row] = wv.z;
      Wt[(4 * j + 3) * 68 + row] = wv.w;
    }
    __syncthreads();
#pragma unroll
    for (int dk = 0; dk < 64; ++dk) {
      float4 a4 = *(const float4*)&At[dk * 68 + ty * 4];
      float4 w4 = *(const float4*)&Wt[dk * 68 + tx * 4];
      const float ar[4] = {a4.x, a4.y, a4.z, a4.w};
      const float wr[4] = {w4.x, w4.y, w4.z, w4.w};
#pragma unroll
      for (int rr = 0; rr < 4; ++rr)
#pragma unroll
        for (int cc = 0; cc < 4; ++cc)
          acc[rr][cc] = fmaf(ar[rr], wr[cc], acc[rr][cc]);
    }
  }

  if (isq) {
    float4 bv = *(const float4*)(b1 + h0 + tx * 4);
    const float br[4] = {bv.x, bv.y, bv.z, bv.w};
#pragma unroll
    for (int rr = 0; rr < 4; ++rr) {
      int r = r0 + ty * 4 + rr;
      float4 ov;
      ov.x = __builtin_amdgcn_exp2f((acc[rr][0] + br[0]) * CSCALE);
      ov.y = __builtin_amdgcn_exp2f((acc[rr][1] + br[1]) * CSCALE);
      ov.z = __builtin_amdgcn_exp2f((acc[rr][2] + br[2]) * CSCALE);
      ov.w = __builtin_amdgcn_exp2f((acc[rr][3] + br[3]) * CSCALE);
      *(float4*)(Eq + (size_t)r * DIM + h0 + tx * 4) = ov;
    }
  } else {
    // Ek4 layout (compacted): Ek4[((b*64 + h/4)*NI + pos[i])*4 + (h&3)]
    int ig0 = r0 - BATCH * NO;
    int b   = ig0 >> 9;
    int i0  = (ig0 & 511) + ty * 4;
    int hq0 = (h0 >> 2) + tx;          // this thread's h-quad
#pragma unroll
    for (int rr = 0; rr < 4; ++rr) {
      int pos = posArr[b * NI + i0 + rr];
      if (pos >= 0) {
        float4 ov;
        ov.x = __builtin_amdgcn_exp2f(acc[rr][0] * CSCALE);
        ov.y = __builtin_amdgcn_exp2f(acc[rr][1] * CSCALE);
        ov.z = __builtin_amdgcn_exp2f(acc[rr][2] * CSCALE);
        ov.w = __builtin_amdgcn_exp2f(acc[rr][3] * CSCALE);
        *(float4*)(Ek4 + ((size_t)(b * 64 + hq0) * NI + pos) * 4) = ov;
      }
    }
  }
}

__device__ __forceinline__ void f4arr(float4 v, float* a) {
  a[0] = v.x; a[1] = v.y; a[2] = v.z; a[3] = v.w;
}

// ---------------------------------------------------------------------------
// Kernel 2: one block (512 threads) per (b, o-pair). Grid 512. XCD-swizzled.
// MASK-COMPACTED: thread j < cnt[b] handles the j-th UNMASKED column only.
// phase 1: paired-rcp sigmoid over compacted Ek4 (coalesced).
// phase 2: softmax over compacted set, no max-subtraction; attn_out scattered
//          back via pos (masked -> exact 0).
// phase 3: PV over compacted rows (row base via LDS idx, coalesced in d).
// phase 4: both o's per thread, shared WfT column.
// ---------------------------------------------------------------------------
__global__ __launch_bounds__(512, 4) void attn_kernel(
    const float* __restrict__ Eq, const float* __restrict__ Ek4,
    const float* __restrict__ v, const int* __restrict__ idx,
    const int* __restrict__ posArr, const int* __restrict__ cnt,
    const float* __restrict__ W2, const float* __restrict__ b2,
    const float* __restrict__ WfT, const float* __restrict__ bf,
    float* __restrict__ out, float* __restrict__ attn_out)
{
  __shared__ float sc[OT][NI];        // 4 KB (compacted attn weights)
  __shared__ int   idxs[NI];          // 2 KB
  __shared__ float pvp[8][OT][DIM];   // 16 KB
  __shared__ float o0[OT][DIM];       // 2 KB
  __shared__ float red4[8][OT];
  __shared__ float redw[8];

  const int t    = threadIdx.x;
  const int lane = t & 63;
  const int wid  = t >> 6;

  const int blk  = blockIdx.x;
  const int tile = (blk & 7) * 64 + (blk >> 3);   // XCD swizzle
  const int b    = tile >> 5;
  const int bo0  = b * 64 + (tile & 31) * OT;

  const int cntb = cnt[b];
  idxs[t] = idx[b * NI + t];
  const int myPos = posArr[b * NI + t];    // for attn_out scatter-back

  // ---- sumW2 ----
  float partial = (t < DIM) ? W2[t] : 0.f;
#pragma unroll
  for (int off = 32; off >= 1; off >>= 1) partial += __shfl_xor(partial, off, 64);
  if (lane == 0) redw[wid] = partial;
  __syncthreads();
  float sumw2 = 0.f;
#pragma unroll
  for (int w = 0; w < 8; ++w) sumw2 += redw[w];
  const float base = sumw2 + b2[0];

  // ---- phase 1: scores for compacted column j = t (paired-rcp) ----
  const int j = t;
  const bool active = (j < cntb);
  const int jc = active ? j : (cntb > 0 ? cntb - 1 : 0);   // clamped safe index
  const float4* kb4 = (const float4*)Ek4 + (size_t)b * 64 * NI;  // [hq*NI + j]
  const float* qrow0 = Eq + (size_t)(bo0 + 0) * DIM;
  const float* qrow1 = Eq + (size_t)(bo0 + 1) * DIM;

  float acc0 = 0.f, acc1 = 0.f;
  if (wid * 64 < cntb) {                 // wave-uniform skip of dead waves
#pragma unroll 8
    for (int hq = 0; hq < 64; ++hq) {
      float4 kq = kb4[(size_t)hq * NI + jc];
      float wr[4], q0r[4], q1r[4], kv[4];
      f4arr(*(const float4*)(W2 + hq * 4), wr);      // wave-uniform -> s_load
      f4arr(*(const float4*)(qrow0 + hq * 4), q0r);
      f4arr(*(const float4*)(qrow1 + hq * 4), q1r);
      f4arr(kq, kv);
#pragma unroll
      for (int pr = 0; pr < 2; ++pr) {               // pairs (0,1), (2,3)
        const int ea = pr * 2, eb = pr * 2 + 1;
        float A0 = fmaf(q0r[ea], kv[ea], 1.f);
        float B0 = fmaf(q0r[eb], kv[eb], 1.f);
        float N0 = fmaf(wr[eb], A0, wr[ea] * B0);
        acc0 = fmaf(N0, __builtin_amdgcn_rcpf(A0 * B0), acc0);
        float A1 = fmaf(q1r[ea], kv[ea], 1.f);
        float B1 = fmaf(q1r[eb], kv[eb], 1.f);
        float N1 = fmaf(wr[eb], A1, wr[ea] * B1);
        acc1 = fmaf(N1, __builtin_amdgcn_rcpf(A1 * B1), acc1);
      }
    }
  }

  float s0 = active ? (base - 2.f * acc0) : -INFINITY;
  float s1 = active ? (base - 2.f * acc1) : -INFINITY;

  // ---- phase 2: softmax over compacted set, no max-subtraction ----
  // |s| <= sum|W2| + |b2| ~ 13 -> exp2 safe; exp2(-inf) = 0 for inactive.
  float p0 = __builtin_amdgcn_exp2f(s0 * 1.4426950408889634f);
  float p1 = __builtin_amdgcn_exp2f(s1 * 1.4426950408889634f);
  float ps0 = p0, ps1 = p1;
#pragma unroll
  for (int off = 32; off >= 1; off >>= 1) {
    ps0 += __shfl_xor(ps0, off, 64);
    ps1 += __shfl_xor(ps1, off, 64);
  }
  __syncthreads();               // redw reads done; red4 safe
  if (lane == 0) { red4[wid][0] = ps0; red4[wid][1] = ps1; }
  __syncthreads();
  float ss0 = 0.f, ss1 = 0.f;
#pragma unroll
  for (int w = 0; w < 8; ++w) { ss0 += red4[w][0]; ss1 += red4[w][1]; }
  const float a0 = p0 * __builtin_amdgcn_rcpf(ss0);
  const float a1 = p1 * __builtin_amdgcn_rcpf(ss1);
  sc[0][j] = a0;                 // compacted slot (0 for inactive j)
  sc[1][j] = a1;
  __syncthreads();

  // attn_out scatter-back: original column i = t; masked -> exact 0
  {
    float w0 = (myPos >= 0) ? sc[0][myPos] : 0.f;
    float w1 = (myPos >= 0) ? sc[1][myPos] : 0.f;
    attn_out[(size_t)(bo0 + 0) * NI + t] = w0;
    attn_out[(size_t)(bo0 + 1) * NI + t] = w1;
  }

  // ---- phase 3: PV over compacted rows. wave wid: j in [wid*64, +64)∩cnt ----
  {
    const int d4 = lane;
    float4 av0 = {0.f, 0.f, 0.f, 0.f};
    float4 av1 = {0.f, 0.f, 0.f, 0.f};
    const float4* vb4 = (const float4*)(v + (size_t)b * NI * DIM);
    const int jend = min(wid * 64 + 64, cntb);
#pragma unroll 4
    for (int jb = wid * 64; jb < jend; ++jb) {
      int row = idxs[jb];                      // LDS broadcast (uniform)
      float sa0 = sc[0][jb], sa1 = sc[1][jb];  // LDS broadcast
      float4 vv = vb4[(size_t)row * 64 + d4];
      av0.x = fmaf(sa0, vv.x, av0.x);
      av0.y = fmaf(sa0, vv.y, av0.y);
      av0.z = fmaf(sa0, vv.z, av0.z);
      av0.w = fmaf(sa0, vv.w, av0.w);
      av1.x = fmaf(sa1, vv.x, av1.x);
      av1.y = fmaf(sa1, vv.y, av1.y);
      av1.z = fmaf(sa1, vv.z, av1.z);
      av1.w = fmaf(sa1, vv.w, av1.w);
    }
    *(float4*)&pvp[wid][0][d4 * 4] = av0;      // dead waves store zeros
    *(float4*)&pvp[wid][1][d4 * 4] = av1;
  }
  __syncthreads();
  {
    int oo = t >> 8, d = t & 255;
    float sacc = 0.f;
#pragma unroll
    for (int w = 0; w < 8; ++w) sacc += pvp[w][oo][d];
    o0[oo][d] = sacc;
  }
  __syncthreads();

  // ---- phase 4: threads t<256 compute BOTH o's, one WfT column load ----
  if (t < DIM) {
    const int d = t;
    float f0 = 0.f, f1 = 0.f;
#pragma unroll 8
    for (int e4 = 0; e4 < 64; ++e4) {
      float oa[4], ob[4];
      f4arr(*(const float4*)&o0[0][e4 * 4], oa);
      f4arr(*(const float4*)&o0[1][e4 * 4], ob);
#pragma unroll
      for (int c = 0; c < 4; ++c) {
        float wv = WfT[(size_t)(e4 * 4 + c) * DIM + d];
        f0 = fmaf(oa[c], wv, f0);
        f1 = fmaf(ob[c], wv, f1);
      }
    }
    float bfv = bf[d];
    f0 += bfv; f1 += bfv;
    f0 = (f0 >= 0.f) ? f0 : NEG_SLOPE * f0;
    f1 = (f1 >= 0.f) ? f1 : NEG_SLOPE * f1;
    out[(size_t)(bo0 + 0) * DIM + d] = f0;
    out[(size_t)(bo0 + 1) * DIM + d] = f1;
  }
}

// ---------------------------------------------------------------------------
extern "C" void kernel_launch(void* const* d_in, const int* in_sizes, int n_in,
                              void* d_out, int out_size, void* d_ws, size_t ws_size,
                              hipStream_t stream) {
  const float* q    = (const float*)d_in[0];
  const float* k    = (const float*)d_in[1];
  const float* v    = (const float*)d_in[2];
  const int*   mask = (const int*)d_in[3];
  const float* W1   = (const float*)d_in[4];
  const float* b1   = (const float*)d_in[5];
  const float* W2   = (const float*)d_in[6];
  const float* b2   = (const float*)d_in[7];
  const float* Wf   = (const float*)d_in[8];
  const float* bf   = (const float*)d_in[9];

  float* out      = (float*)d_out;                    // (16,64,256)
  float* attn_out = out + (size_t)BATCH * NO * DIM;   // (16,64,512)

  float* Eq   = (float*)d_ws;                         // 1024 x 256
  float* Ek4  = Eq + (size_t)BATCH * NO * DIM;        // 16 x 64 x 512 x 4
  float* WfT  = Ek4 + (size_t)BATCH * DIM * NI;       // 256 x 256
  int*   idx  = (int*)(WfT + (size_t)DIM * DIM);      // 16 x 512
  int*   pos  = idx + BATCH * NI;                     // 16 x 512
  int*   cnt  = pos + BATCH * NI;                     // 16

  mask_scan_kernel<<<BATCH, 512, 0, stream>>>(mask, idx, pos, cnt);
  proj_kernel<<<592, 256, 0, stream>>>(q, k, W1, b1, Wf, pos, Eq, Ek4, WfT);
  attn_kernel<<<(BATCH * NO) / OT, 512, 0, stream>>>(Eq, Ek4, v, idx, pos, cnt,
                                                     W2, b2, WfT, bf, out, attn_out);
}